// Round 1
// baseline (710.918 us; speedup 1.0000x reference)
//
#include <hip/hip_runtime.h>

typedef unsigned short u16;
typedef __bf16 bf16x8 __attribute__((ext_vector_type(8)));
typedef float floatx4 __attribute__((ext_vector_type(4)));

#define B_ 2
#define L_ 2048
#define S_ 2048
#define D_ 512
#define H_ 8

static __device__ __forceinline__ u16 f2bf(float f) {
  union { float f; unsigned u; } v; v.f = f;
  unsigned u = v.u;
  return (u16)((u + 0x7FFFu + ((u >> 16) & 1u)) >> 16);  // RNE
}
static __device__ __forceinline__ float bf2f(u16 h) {
  union { unsigned u; float f; } v; v.u = ((unsigned)h) << 16;
  return v.f;
}

// ---------------------------------------------------------------------------
// QKV projection GEMM: C[m][n] = sum_k A[m][k] * W[n][k]   (M=4096,N=512,K=512)
// blockIdx.z selects: 0 queries->q (fp32), 1 keys->kb (bf16), 2 values->vb (bf16,+bv)
// 128x128 tile, 4 waves, 16x16x32 bf16 MFMA, fp32->bf16 convert at LDS staging.
// ---------------------------------------------------------------------------
__global__ __launch_bounds__(256) void qkv_gemm(
    const float* __restrict__ Qin, const float* __restrict__ Kin, const float* __restrict__ Vin,
    const float* __restrict__ Wq, const float* __restrict__ Wk, const float* __restrict__ Wv,
    const float* __restrict__ bv,
    float* __restrict__ qo, u16* __restrict__ ko, u16* __restrict__ vo)
{
  __shared__ u16 As[128][72];   // row stride 144B = 9*16B: aligned b128, banks spread
  __shared__ u16 Bs[128][72];
  const int z = blockIdx.z;
  const float* A = (z == 0) ? Qin : (z == 1) ? Kin : Vin;
  const float* W = (z == 0) ? Wq : (z == 1) ? Wk : Wv;
  const int tid = threadIdx.x;
  const int m0 = blockIdx.y * 128;
  const int n0 = blockIdx.x * 128;
  const int lane = tid & 63, w = tid >> 6;
  const int ml = lane & 15, kl = lane >> 4;
  const int mq = (w >> 1) * 64, nq = (w & 1) * 64;
  const int srow = tid >> 4, scg = tid & 15;

  floatx4 acc[4][4] = {};

  for (int k0 = 0; k0 < 512; k0 += 64) {
#pragma unroll
    for (int i = 0; i < 8; ++i) {
      const int r = srow + i * 16;
      float4 av = *(const float4*)&A[(size_t)(m0 + r) * 512 + k0 + scg * 4];
      ushort4 ua; ua.x = f2bf(av.x); ua.y = f2bf(av.y); ua.z = f2bf(av.z); ua.w = f2bf(av.w);
      *(ushort4*)&As[r][scg * 4] = ua;
      float4 wv = *(const float4*)&W[(size_t)(n0 + r) * 512 + k0 + scg * 4];
      ushort4 uw; uw.x = f2bf(wv.x); uw.y = f2bf(wv.y); uw.z = f2bf(wv.z); uw.w = f2bf(wv.w);
      *(ushort4*)&Bs[r][scg * 4] = uw;
    }
    __syncthreads();
#pragma unroll
    for (int kk = 0; kk < 64; kk += 32) {
      bf16x8 af[4], bfv[4];
#pragma unroll
      for (int i = 0; i < 4; ++i) af[i] = *(const bf16x8*)&As[mq + i * 16 + ml][kk + kl * 8];
#pragma unroll
      for (int j = 0; j < 4; ++j) bfv[j] = *(const bf16x8*)&Bs[nq + j * 16 + ml][kk + kl * 8];
#pragma unroll
      for (int i = 0; i < 4; ++i)
#pragma unroll
        for (int j = 0; j < 4; ++j)
          acc[i][j] = __builtin_amdgcn_mfma_f32_16x16x32_bf16(af[i], bfv[j], acc[i][j], 0, 0, 0);
    }
    __syncthreads();
  }
#pragma unroll
  for (int i = 0; i < 4; ++i)
#pragma unroll
    for (int j = 0; j < 4; ++j) {
      const int gc = n0 + nq + j * 16 + ml;
#pragma unroll
      for (int r = 0; r < 4; ++r) {
        const int gr = m0 + mq + i * 16 + kl * 4 + r;  // C/D: row=(lane>>4)*4+r, col=lane&15
        float v = acc[i][j][r];
        if (z == 0)      qo[(size_t)gr * 512 + gc] = v;
        else if (z == 1) ko[(size_t)gr * 512 + gc] = f2bf(v);
        else             vo[(size_t)gr * 512 + gc] = f2bf(v + bv[gc]);
      }
    }
}

// ---------------------------------------------------------------------------
// Output projection GEMM: out[m][n] = sum_k ctx[m][k]*Wd[n][k] + bd[n]  (fp32 out)
// ---------------------------------------------------------------------------
__global__ __launch_bounds__(256) void out_gemm(
    const float* __restrict__ A, const float* __restrict__ W,
    const float* __restrict__ bias, float* __restrict__ out)
{
  __shared__ u16 As[128][72];
  __shared__ u16 Bs[128][72];
  const int tid = threadIdx.x;
  const int m0 = blockIdx.y * 128;
  const int n0 = blockIdx.x * 128;
  const int lane = tid & 63, w = tid >> 6;
  const int ml = lane & 15, kl = lane >> 4;
  const int mq = (w >> 1) * 64, nq = (w & 1) * 64;
  const int srow = tid >> 4, scg = tid & 15;

  floatx4 acc[4][4] = {};

  for (int k0 = 0; k0 < 512; k0 += 64) {
#pragma unroll
    for (int i = 0; i < 8; ++i) {
      const int r = srow + i * 16;
      float4 av = *(const float4*)&A[(size_t)(m0 + r) * 512 + k0 + scg * 4];
      ushort4 ua; ua.x = f2bf(av.x); ua.y = f2bf(av.y); ua.z = f2bf(av.z); ua.w = f2bf(av.w);
      *(ushort4*)&As[r][scg * 4] = ua;
      float4 wv = *(const float4*)&W[(size_t)(n0 + r) * 512 + k0 + scg * 4];
      ushort4 uw; uw.x = f2bf(wv.x); uw.y = f2bf(wv.y); uw.z = f2bf(wv.z); uw.w = f2bf(wv.w);
      *(ushort4*)&Bs[r][scg * 4] = uw;
    }
    __syncthreads();
#pragma unroll
    for (int kk = 0; kk < 64; kk += 32) {
      bf16x8 af[4], bfv[4];
#pragma unroll
      for (int i = 0; i < 4; ++i) af[i] = *(const bf16x8*)&As[mq + i * 16 + ml][kk + kl * 8];
#pragma unroll
      for (int j = 0; j < 4; ++j) bfv[j] = *(const bf16x8*)&Bs[nq + j * 16 + ml][kk + kl * 8];
#pragma unroll
      for (int i = 0; i < 4; ++i)
#pragma unroll
        for (int j = 0; j < 4; ++j)
          acc[i][j] = __builtin_amdgcn_mfma_f32_16x16x32_bf16(af[i], bfv[j], acc[i][j], 0, 0, 0);
    }
    __syncthreads();
  }
#pragma unroll
  for (int i = 0; i < 4; ++i)
#pragma unroll
    for (int j = 0; j < 4; ++j) {
      const int gc = n0 + nq + j * 16 + ml;
#pragma unroll
      for (int r = 0; r < 4; ++r) {
        const int gr = m0 + mq + i * 16 + kl * 4 + r;
        out[(size_t)gr * 512 + gc] = acc[i][j][r] + bias[gc];
      }
    }
}

// ---------------------------------------------------------------------------
// Content bias: cb[b][h][s] = sum_d keys[b][s][d] * Wcb[h][d]  (one wave per (b,s))
// ---------------------------------------------------------------------------
__global__ __launch_bounds__(256) void cb_kernel(
    const float* __restrict__ keys, const float* __restrict__ Wcb, float* __restrict__ cbuf)
{
  __shared__ float Wl[8 * 512];
  const int tid = threadIdx.x;
#pragma unroll
  for (int i = 0; i < 4; ++i) {
    const int idx = tid + i * 256;
    *(float4*)&Wl[idx * 4] = *(const float4*)&Wcb[idx * 4];
  }
  __syncthreads();
  const int w = tid >> 6, lane = tid & 63;
  const int rowid = blockIdx.x * 4 + w;           // 0..4095 = b*2048+s
  const int b = rowid >> 11, s = rowid & 2047;
  const float* kr = keys + (size_t)rowid * 512;
  float acc[8] = {0.f, 0.f, 0.f, 0.f, 0.f, 0.f, 0.f, 0.f};
  for (int e = lane; e < 512; e += 64) {
    const float kv = kr[e];
#pragma unroll
    for (int hh = 0; hh < 8; ++hh) acc[hh] += kv * Wl[hh * 512 + e];
  }
#pragma unroll
  for (int hh = 0; hh < 8; ++hh) {
#pragma unroll
    for (int off = 32; off > 0; off >>= 1) acc[hh] += __shfl_xor(acc[hh], off, 64);
  }
  if (lane == 0) {
#pragma unroll
    for (int hh = 0; hh < 8; ++hh)
      cbuf[((size_t)b * 8 + hh) * 2048 + s] = acc[hh];
  }
}

// ---------------------------------------------------------------------------
// Transpose v: vb [B][S][512] bf16 -> vT [B][512][S] bf16 (64x64 tiles via LDS)
// ---------------------------------------------------------------------------
__global__ __launch_bounds__(256) void transpose_v(
    const u16* __restrict__ vb, u16* __restrict__ vT)
{
  __shared__ u16 t[64][72];
  const int tid = threadIdx.x;
  const int e0 = blockIdx.x * 64;
  const int s0 = blockIdx.y * 64;
  const int b = blockIdx.z;
  const int rr = tid >> 3, g = tid & 7;
#pragma unroll
  for (int i = 0; i < 2; ++i) {
    const int r = rr + i * 32;
    *(uint4*)&t[r][g * 8] = *(const uint4*)&vb[((size_t)b * S_ + s0 + r) * 512 + e0 + g * 8];
  }
  __syncthreads();
#pragma unroll
  for (int i = 0; i < 2; ++i) {
    const int er = rr + i * 32;
    uint4 o;
    o.x = (unsigned)t[g * 8 + 0][er] | ((unsigned)t[g * 8 + 1][er] << 16);
    o.y = (unsigned)t[g * 8 + 2][er] | ((unsigned)t[g * 8 + 3][er] << 16);
    o.z = (unsigned)t[g * 8 + 4][er] | ((unsigned)t[g * 8 + 5][er] << 16);
    o.w = (unsigned)t[g * 8 + 6][er] | ((unsigned)t[g * 8 + 7][er] << 16);
    *(uint4*)&vT[((size_t)b * 512 + e0 + er) * S_ + s0 + g * 8] = o;
  }
}

// ---------------------------------------------------------------------------
// Scores GEMM (per b,h): sc[l][s] = (sum_e q[l][e]*mix[h][e]*k[s][e] + cb[s]) / 8
// mixing folded into A-staging (fp32 mult, then bf16). Raw fp32 scores written
// into the probs region of d_out (overwritten by softmax_ctx afterwards).
// ---------------------------------------------------------------------------
__global__ __launch_bounds__(256) void scores_gemm(
    const float* __restrict__ q, const u16* __restrict__ kb,
    const float* __restrict__ mixing, const float* __restrict__ cbuf,
    float* __restrict__ sc)
{
  __shared__ u16 As[128][72];
  __shared__ u16 Bs[128][72];
  __shared__ float mixs[512];
  const int tid = threadIdx.x;
  const int bh = blockIdx.z, b = bh >> 3, h = bh & 7;
  const int m0 = blockIdx.y * 128;   // l tile
  const int n0 = blockIdx.x * 128;   // s tile
  *(float2*)&mixs[tid * 2] = *(const float2*)&mixing[(size_t)h * 512 + tid * 2];
  const float* qb = q + (size_t)b * L_ * 512;
  const u16* kbb = kb + (size_t)b * S_ * 512;
  const int lane = tid & 63, w = tid >> 6;
  const int ml = lane & 15, kl = lane >> 4;
  const int mq = (w >> 1) * 64, nq = (w & 1) * 64;
  const int srow = tid >> 4, scg = tid & 15;
  const int brow = tid >> 3, bcg = tid & 7;

  floatx4 acc[4][4] = {};

  __syncthreads();   // mixs visible before first A staging
  for (int k0 = 0; k0 < 512; k0 += 64) {
#pragma unroll
    for (int i = 0; i < 8; ++i) {
      const int r = srow + i * 16;
      float4 av = *(const float4*)&qb[(size_t)(m0 + r) * 512 + k0 + scg * 4];
      const float4 mv = *(const float4*)&mixs[k0 + scg * 4];
      ushort4 ua;
      ua.x = f2bf(av.x * mv.x); ua.y = f2bf(av.y * mv.y);
      ua.z = f2bf(av.z * mv.z); ua.w = f2bf(av.w * mv.w);
      *(ushort4*)&As[r][scg * 4] = ua;
    }
#pragma unroll
    for (int i = 0; i < 4; ++i) {
      const int r = brow + i * 32;
      *(uint4*)&Bs[r][bcg * 8] = *(const uint4*)&kbb[(size_t)(n0 + r) * 512 + k0 + bcg * 8];
    }
    __syncthreads();
#pragma unroll
    for (int kk = 0; kk < 64; kk += 32) {
      bf16x8 af[4], bfv[4];
#pragma unroll
      for (int i = 0; i < 4; ++i) af[i] = *(const bf16x8*)&As[mq + i * 16 + ml][kk + kl * 8];
#pragma unroll
      for (int j = 0; j < 4; ++j) bfv[j] = *(const bf16x8*)&Bs[nq + j * 16 + ml][kk + kl * 8];
#pragma unroll
      for (int i = 0; i < 4; ++i)
#pragma unroll
        for (int j = 0; j < 4; ++j)
          acc[i][j] = __builtin_amdgcn_mfma_f32_16x16x32_bf16(af[i], bfv[j], acc[i][j], 0, 0, 0);
    }
    __syncthreads();
  }
  float* outp = sc + ((size_t)bh * L_ + m0) * S_ + n0;
#pragma unroll
  for (int j = 0; j < 4; ++j) {
    const int gcl = nq + j * 16 + ml;
    const float cbv = cbuf[(size_t)bh * S_ + n0 + gcl];
#pragma unroll
    for (int i = 0; i < 4; ++i)
#pragma unroll
      for (int r = 0; r < 4; ++r) {
        const int grl = mq + i * 16 + kl * 4 + r;
        outp[(size_t)grl * S_ + gcl] = (acc[i][j][r] + cbv) * 0.125f;
      }
  }
}

// ---------------------------------------------------------------------------
// Softmax + probs write + ctx = P @ Vhead.  16 rows per block; each thread keeps
// its slice of the row (128 values) as packed bf16 in 64 VGPRs; probs written
// in place over the raw scores; ctx accumulated with 16x16x32 MFMA over 64-wide
// s-chunks streamed through small LDS buffers.
// ---------------------------------------------------------------------------
__global__ __launch_bounds__(256) void softmax_ctx(
    float* __restrict__ sc, const u16* __restrict__ vT, float* __restrict__ ctx)
{
  __shared__ u16 Ps[16][72];
  __shared__ u16 Vs[64][72];
  __shared__ float mrow[16], lrow[16];
  const int tid = threadIdx.x;
  const int bh = blockIdx.y, b = bh >> 3, h = bh & 7;
  const int l0 = blockIdx.x * 16;
  float* Sg = sc + ((size_t)bh * L_ + l0) * S_;
  const int row = tid >> 4, jg = tid & 15;   // 16 threads per row

  unsigned pr[64];                            // row slice, packed bf16 x2
  float mx = -3.0e38f;
#pragma unroll
  for (int i = 0; i < 32; ++i) {
    const int c = jg * 4 + i * 64;
    float4 v = *(const float4*)&Sg[(size_t)row * S_ + c];
    pr[2 * i]     = (unsigned)f2bf(v.x) | ((unsigned)f2bf(v.y) << 16);
    pr[2 * i + 1] = (unsigned)f2bf(v.z) | ((unsigned)f2bf(v.w) << 16);
    mx = fmaxf(mx, fmaxf(fmaxf(v.x, v.y), fmaxf(v.z, v.w)));
  }
#pragma unroll
  for (int off = 8; off > 0; off >>= 1) mx = fmaxf(mx, __shfl_xor(mx, off, 64));
  if (jg == 0) mrow[row] = mx;
  __syncthreads();
  const float m = mrow[row];
  float ls = 0.f;
#pragma unroll
  for (int i = 0; i < 64; ++i) {
    const unsigned u = pr[i];
    ls += __expf(bf2f((u16)(u & 0xFFFFu)) - m) + __expf(bf2f((u16)(u >> 16)) - m);
  }
#pragma unroll
  for (int off = 8; off > 0; off >>= 1) ls += __shfl_xor(ls, off, 64);
  if (jg == 0) lrow[row] = ls;
  __syncthreads();
  const float rl = 1.0f / lrow[row];
#pragma unroll
  for (int i = 0; i < 32; ++i) {
    const int c = jg * 4 + i * 64;
    const unsigned u0 = pr[2 * i], u1 = pr[2 * i + 1];
    float4 p;
    p.x = __expf(bf2f((u16)(u0 & 0xFFFFu)) - m) * rl;
    p.y = __expf(bf2f((u16)(u0 >> 16)) - m) * rl;
    p.z = __expf(bf2f((u16)(u1 & 0xFFFFu)) - m) * rl;
    p.w = __expf(bf2f((u16)(u1 >> 16)) - m) * rl;
    *(float4*)&Sg[(size_t)row * S_ + c] = p;   // final probs out
    pr[2 * i]     = (unsigned)f2bf(p.x) | ((unsigned)f2bf(p.y) << 16);
    pr[2 * i + 1] = (unsigned)f2bf(p.z) | ((unsigned)f2bf(p.w) << 16);
  }
  // ctx[l0..l0+15][h*64 + 0..63] = P(16 x 2048) @ V(2048 x 64)
  const int lane = tid & 63, wv = tid >> 6;
  const int ml = lane & 15, kl = lane >> 4;
  const int vr = tid >> 3, vg = tid & 7;
  floatx4 acc = {};
  const u16* vhead = vT + ((size_t)b * 512 + h * 64) * S_;
#pragma unroll
  for (int ci = 0; ci < 32; ++ci) {
    const int s0 = ci * 64;
    __syncthreads();   // previous chunk's MFMA reads done before overwrite
    {
      uint2 t; t.x = pr[2 * ci]; t.y = pr[2 * ci + 1];
      *(uint2*)&Ps[row][jg * 4] = t;
#pragma unroll
      for (int i = 0; i < 2; ++i) {
        const int r = vr + i * 32;
        *(uint4*)&Vs[r][vg * 8] = *(const uint4*)&vhead[(size_t)r * S_ + s0 + vg * 8];
      }
    }
    __syncthreads();
#pragma unroll
    for (int kk = 0; kk < 64; kk += 32) {
      bf16x8 a  = *(const bf16x8*)&Ps[ml][kk + kl * 8];
      bf16x8 bb = *(const bf16x8*)&Vs[wv * 16 + ml][kk + kl * 8];
      acc = __builtin_amdgcn_mfma_f32_16x16x32_bf16(a, bb, acc, 0, 0, 0);
    }
  }
#pragma unroll
  for (int r = 0; r < 4; ++r) {
    const int gr = l0 + kl * 4 + r;
    const int gc = h * 64 + wv * 16 + ml;
    ctx[((size_t)b * L_ + gr) * 512 + gc] = acc[r];
  }
}

// ---------------------------------------------------------------------------
extern "C" void kernel_launch(void* const* d_in, const int* in_sizes, int n_in,
                              void* d_out, int out_size, void* d_ws, size_t ws_size,
                              hipStream_t stream) {
  const float* queries = (const float*)d_in[0];
  const float* keys    = (const float*)d_in[1];
  const float* values  = (const float*)d_in[2];
  // d_in[3] attn_mask: unused (always 0 in reference)
  const float* Wq  = (const float*)d_in[4];
  const float* Wk  = (const float*)d_in[5];
  const float* Wv  = (const float*)d_in[6];
  const float* bv  = (const float*)d_in[7];
  const float* Wcb = (const float*)d_in[8];
  const float* mixing = (const float*)d_in[9];
  const float* Wd  = (const float*)d_in[10];
  const float* bd  = (const float*)d_in[11];

  float* out   = (float*)d_out;                         // [B,L,512] fp32
  float* probs = out + (size_t)B_ * L_ * 512;           // [B,H,L,S] fp32

  char* ws = (char*)d_ws;
  float* q   = (float*)(ws);                            //  8 MB  fp32 [B*L,512]
  u16*   kb  = (u16*)(ws + (size_t)8  * 1024 * 1024);   //  4 MB  bf16 [B*S,512]
  u16*   vb  = (u16*)(ws + (size_t)12 * 1024 * 1024);   //  4 MB  bf16 [B*S,512]
  u16*   vT  = (u16*)(ws + (size_t)16 * 1024 * 1024);   //  4 MB  bf16 [B,512,S]
  float* cbuf= (float*)(ws + (size_t)20 * 1024 * 1024); // 128 KB fp32 [B,H,S]
  float* ctx = (float*)(ws + (size_t)21 * 1024 * 1024); //  8 MB  fp32 [B*L,512]

  hipLaunchKernelGGL(qkv_gemm, dim3(4, 32, 3), dim3(256), 0, stream,
                     queries, keys, values, Wq, Wk, Wv, bv, q, kb, vb);
  hipLaunchKernelGGL(cb_kernel, dim3(1024), dim3(256), 0, stream, keys, Wcb, cbuf);
  hipLaunchKernelGGL(transpose_v, dim3(8, 32, 2), dim3(256), 0, stream, vb, vT);
  hipLaunchKernelGGL(scores_gemm, dim3(16, 16, 16), dim3(256), 0, stream,
                     q, kb, mixing, cbuf, probs);
  hipLaunchKernelGGL(softmax_ctx, dim3(128, 16), dim3(256), 0, stream,
                     probs, vT, ctx);
  hipLaunchKernelGGL(out_gemm, dim3(4, 32, 1), dim3(256), 0, stream,
                     ctx, Wd, bd, out);
}

// Round 2
// 677.048 us; speedup vs baseline: 1.0500x; 1.0500x over previous
//
#include <hip/hip_runtime.h>

typedef unsigned short u16;
typedef __bf16 bf16x8 __attribute__((ext_vector_type(8)));
typedef float floatx4 __attribute__((ext_vector_type(4)));

#define B_ 2
#define L_ 2048
#define S_ 2048
#define D_ 512
#define H_ 8

static __device__ __forceinline__ u16 f2bf(float f) {
  union { float f; unsigned u; } v; v.f = f;
  unsigned u = v.u;
  return (u16)((u + 0x7FFFu + ((u >> 16) & 1u)) >> 16);  // RNE
}
static __device__ __forceinline__ float bf2f(u16 h) {
  union { unsigned u; float f; } v; v.u = ((unsigned)h) << 16;
  return v.f;
}

// ---------------------------------------------------------------------------
// QKV projection GEMM: C[m][n] = sum_k A[m][k] * W[n][k]   (M=4096,N=512,K=512)
// z: 0 queries->qb (bf16), 1 keys->kb (bf16), 2 values->vb (bf16,+bv)
// ---------------------------------------------------------------------------
__global__ __launch_bounds__(256) void qkv_gemm(
    const float* __restrict__ Qin, const float* __restrict__ Kin, const float* __restrict__ Vin,
    const float* __restrict__ Wq, const float* __restrict__ Wk, const float* __restrict__ Wv,
    const float* __restrict__ bv,
    u16* __restrict__ qo, u16* __restrict__ ko, u16* __restrict__ vo)
{
  __shared__ u16 As[128][72];
  __shared__ u16 Bs[128][72];
  const int z = blockIdx.z;
  const float* A = (z == 0) ? Qin : (z == 1) ? Kin : Vin;
  const float* W = (z == 0) ? Wq : (z == 1) ? Wk : Wv;
  const int tid = threadIdx.x;
  const int m0 = blockIdx.y * 128;
  const int n0 = blockIdx.x * 128;
  const int lane = tid & 63, w = tid >> 6;
  const int ml = lane & 15, kl = lane >> 4;
  const int mqw = (w >> 1) * 64, nq = (w & 1) * 64;
  const int srow = tid >> 4, scg = tid & 15;

  floatx4 acc[4][4] = {};

  for (int k0 = 0; k0 < 512; k0 += 64) {
#pragma unroll
    for (int i = 0; i < 8; ++i) {
      const int r = srow + i * 16;
      float4 av = *(const float4*)&A[(size_t)(m0 + r) * 512 + k0 + scg * 4];
      ushort4 ua; ua.x = f2bf(av.x); ua.y = f2bf(av.y); ua.z = f2bf(av.z); ua.w = f2bf(av.w);
      *(ushort4*)&As[r][scg * 4] = ua;
      float4 wv = *(const float4*)&W[(size_t)(n0 + r) * 512 + k0 + scg * 4];
      ushort4 uw; uw.x = f2bf(wv.x); uw.y = f2bf(wv.y); uw.z = f2bf(wv.z); uw.w = f2bf(wv.w);
      *(ushort4*)&Bs[r][scg * 4] = uw;
    }
    __syncthreads();
#pragma unroll
    for (int kk = 0; kk < 64; kk += 32) {
      bf16x8 af[4], bfv[4];
#pragma unroll
      for (int i = 0; i < 4; ++i) af[i] = *(const bf16x8*)&As[mqw + i * 16 + ml][kk + kl * 8];
#pragma unroll
      for (int j = 0; j < 4; ++j) bfv[j] = *(const bf16x8*)&Bs[nq + j * 16 + ml][kk + kl * 8];
#pragma unroll
      for (int i = 0; i < 4; ++i)
#pragma unroll
        for (int j = 0; j < 4; ++j)
          acc[i][j] = __builtin_amdgcn_mfma_f32_16x16x32_bf16(af[i], bfv[j], acc[i][j], 0, 0, 0);
    }
    __syncthreads();
  }
#pragma unroll
  for (int i = 0; i < 4; ++i)
#pragma unroll
    for (int j = 0; j < 4; ++j) {
      const int gc = n0 + nq + j * 16 + ml;
#pragma unroll
      for (int r = 0; r < 4; ++r) {
        const int gr = m0 + mqw + i * 16 + kl * 4 + r;
        float v = acc[i][j][r];
        if (z == 0)      qo[(size_t)gr * 512 + gc] = f2bf(v);
        else if (z == 1) ko[(size_t)gr * 512 + gc] = f2bf(v);
        else             vo[(size_t)gr * 512 + gc] = f2bf(v + bv[gc]);
      }
    }
}

// ---------------------------------------------------------------------------
// mixed_q: mq[b][h][l][e] = bf16( qb[b][l][e] * mixing[h][e] )
// ---------------------------------------------------------------------------
__global__ __launch_bounds__(256) void mixq_kernel(
    const u16* __restrict__ qb, const float* __restrict__ mixing, u16* __restrict__ mq)
{
  __shared__ float mixs[8 * 512];
  const int tid = threadIdx.x;
#pragma unroll
  for (int i = 0; i < 4; ++i)
    *(float4*)&mixs[(tid + i * 256) * 4] = *(const float4*)&mixing[(tid + i * 256) * 4];
  __syncthreads();
  const size_t unit = (size_t)blockIdx.x * 256 + tid;  // one 8-elem group
  const size_t el = unit * 8;
  const int e = (int)(el & 511);
  const size_t bl = el >> 9;
  const int b = (int)(bl >> 11);
  const int l = (int)(bl & 2047);
  uint4 qv = *(const uint4*)&qb[el];
  const float q0 = bf2f((u16)(qv.x & 0xFFFFu)), q1 = bf2f((u16)(qv.x >> 16));
  const float q2 = bf2f((u16)(qv.y & 0xFFFFu)), q3 = bf2f((u16)(qv.y >> 16));
  const float q4 = bf2f((u16)(qv.z & 0xFFFFu)), q5 = bf2f((u16)(qv.z >> 16));
  const float q6 = bf2f((u16)(qv.w & 0xFFFFu)), q7 = bf2f((u16)(qv.w >> 16));
#pragma unroll
  for (int h = 0; h < 8; ++h) {
    const float* mp = &mixs[h * 512 + e];
    uint4 o;
    o.x = (unsigned)f2bf(q0 * mp[0]) | ((unsigned)f2bf(q1 * mp[1]) << 16);
    o.y = (unsigned)f2bf(q2 * mp[2]) | ((unsigned)f2bf(q3 * mp[3]) << 16);
    o.z = (unsigned)f2bf(q4 * mp[4]) | ((unsigned)f2bf(q5 * mp[5]) << 16);
    o.w = (unsigned)f2bf(q6 * mp[6]) | ((unsigned)f2bf(q7 * mp[7]) << 16);
    *(uint4*)&mq[(((size_t)b * 8 + h) * 2048 + l) * 512 + e] = o;
  }
}

// ---------------------------------------------------------------------------
// Output projection GEMM: out[m][n] = sum_k ctx[m][k]*Wd[n][k] + bd[n]
// ---------------------------------------------------------------------------
__global__ __launch_bounds__(256) void out_gemm(
    const float* __restrict__ A, const float* __restrict__ W,
    const float* __restrict__ bias, float* __restrict__ out)
{
  __shared__ u16 As[128][72];
  __shared__ u16 Bs[128][72];
  const int tid = threadIdx.x;
  const int m0 = blockIdx.y * 128;
  const int n0 = blockIdx.x * 128;
  const int lane = tid & 63, w = tid >> 6;
  const int ml = lane & 15, kl = lane >> 4;
  const int mqw = (w >> 1) * 64, nq = (w & 1) * 64;
  const int srow = tid >> 4, scg = tid & 15;

  floatx4 acc[4][4] = {};

  for (int k0 = 0; k0 < 512; k0 += 64) {
#pragma unroll
    for (int i = 0; i < 8; ++i) {
      const int r = srow + i * 16;
      float4 av = *(const float4*)&A[(size_t)(m0 + r) * 512 + k0 + scg * 4];
      ushort4 ua; ua.x = f2bf(av.x); ua.y = f2bf(av.y); ua.z = f2bf(av.z); ua.w = f2bf(av.w);
      *(ushort4*)&As[r][scg * 4] = ua;
      float4 wv = *(const float4*)&W[(size_t)(n0 + r) * 512 + k0 + scg * 4];
      ushort4 uw; uw.x = f2bf(wv.x); uw.y = f2bf(wv.y); uw.z = f2bf(wv.z); uw.w = f2bf(wv.w);
      *(ushort4*)&Bs[r][scg * 4] = uw;
    }
    __syncthreads();
#pragma unroll
    for (int kk = 0; kk < 64; kk += 32) {
      bf16x8 af[4], bfv[4];
#pragma unroll
      for (int i = 0; i < 4; ++i) af[i] = *(const bf16x8*)&As[mqw + i * 16 + ml][kk + kl * 8];
#pragma unroll
      for (int j = 0; j < 4; ++j) bfv[j] = *(const bf16x8*)&Bs[nq + j * 16 + ml][kk + kl * 8];
#pragma unroll
      for (int i = 0; i < 4; ++i)
#pragma unroll
        for (int j = 0; j < 4; ++j)
          acc[i][j] = __builtin_amdgcn_mfma_f32_16x16x32_bf16(af[i], bfv[j], acc[i][j], 0, 0, 0);
    }
    __syncthreads();
  }
#pragma unroll
  for (int i = 0; i < 4; ++i)
#pragma unroll
    for (int j = 0; j < 4; ++j) {
      const int gc = n0 + nq + j * 16 + ml;
#pragma unroll
      for (int r = 0; r < 4; ++r) {
        const int gr = m0 + mqw + i * 16 + kl * 4 + r;
        out[(size_t)gr * 512 + gc] = acc[i][j][r] + bias[gc];
      }
    }
}

// ---------------------------------------------------------------------------
// Content bias: cb[b][h][s] = sum_d keys[b][s][d] * Wcb[h][d]
// ---------------------------------------------------------------------------
__global__ __launch_bounds__(256) void cb_kernel(
    const float* __restrict__ keys, const float* __restrict__ Wcb, float* __restrict__ cbuf)
{
  __shared__ float Wl[8 * 512];
  const int tid = threadIdx.x;
#pragma unroll
  for (int i = 0; i < 4; ++i) {
    const int idx = tid + i * 256;
    *(float4*)&Wl[idx * 4] = *(const float4*)&Wcb[idx * 4];
  }
  __syncthreads();
  const int w = tid >> 6, lane = tid & 63;
  const int rowid = blockIdx.x * 4 + w;
  const int b = rowid >> 11, s = rowid & 2047;
  const float* kr = keys + (size_t)rowid * 512;
  float acc[8] = {0.f, 0.f, 0.f, 0.f, 0.f, 0.f, 0.f, 0.f};
  for (int e = lane; e < 512; e += 64) {
    const float kv = kr[e];
#pragma unroll
    for (int hh = 0; hh < 8; ++hh) acc[hh] += kv * Wl[hh * 512 + e];
  }
#pragma unroll
  for (int hh = 0; hh < 8; ++hh) {
#pragma unroll
    for (int off = 32; off > 0; off >>= 1) acc[hh] += __shfl_xor(acc[hh], off, 64);
  }
  if (lane == 0) {
#pragma unroll
    for (int hh = 0; hh < 8; ++hh)
      cbuf[((size_t)b * 8 + hh) * 2048 + s] = acc[hh];
  }
}

// ---------------------------------------------------------------------------
// Transpose v: vb [B][S][512] bf16 -> vT [B][512][S] bf16
// ---------------------------------------------------------------------------
__global__ __launch_bounds__(256) void transpose_v(
    const u16* __restrict__ vb, u16* __restrict__ vT)
{
  __shared__ u16 t[64][72];
  const int tid = threadIdx.x;
  const int e0 = blockIdx.x * 64;
  const int s0 = blockIdx.y * 64;
  const int b = blockIdx.z;
  const int rr = tid >> 3, g = tid & 7;
#pragma unroll
  for (int i = 0; i < 2; ++i) {
    const int r = rr + i * 32;
    *(uint4*)&t[r][g * 8] = *(const uint4*)&vb[((size_t)b * S_ + s0 + r) * 512 + e0 + g * 8];
  }
  __syncthreads();
#pragma unroll
  for (int i = 0; i < 2; ++i) {
    const int er = rr + i * 32;
    uint4 o;
    o.x = (unsigned)t[g * 8 + 0][er] | ((unsigned)t[g * 8 + 1][er] << 16);
    o.y = (unsigned)t[g * 8 + 2][er] | ((unsigned)t[g * 8 + 3][er] << 16);
    o.z = (unsigned)t[g * 8 + 4][er] | ((unsigned)t[g * 8 + 5][er] << 16);
    o.w = (unsigned)t[g * 8 + 6][er] | ((unsigned)t[g * 8 + 7][er] << 16);
    *(uint4*)&vT[((size_t)b * 512 + e0 + er) * S_ + s0 + g * 8] = o;
  }
}

// ---------------------------------------------------------------------------
// Scores GEMM (per b,h): sc[l][s] = (sum_e mq[bh][l][e]*k[s][e] + cb[s]) / 8
// A is precomputed bf16 mixed_q -> staging is a pure uint4 copy.
// ---------------------------------------------------------------------------
__global__ __launch_bounds__(256) void scores_gemm(
    const u16* __restrict__ mq, const u16* __restrict__ kb,
    const float* __restrict__ cbuf, float* __restrict__ sc)
{
  __shared__ u16 As[128][72];
  __shared__ u16 Bs[128][72];
  const int tid = threadIdx.x;
  const int bh = blockIdx.z, b = bh >> 3;
  const int m0 = blockIdx.y * 128;
  const int n0 = blockIdx.x * 128;
  const u16* mqb = mq + (size_t)bh * L_ * 512;
  const u16* kbb = kb + (size_t)b * S_ * 512;
  const int lane = tid & 63, w = tid >> 6;
  const int ml = lane & 15, kl = lane >> 4;
  const int mqw = (w >> 1) * 64, nq = (w & 1) * 64;
  const int brow = tid >> 3, bcg = tid & 7;

  floatx4 acc[4][4] = {};

  for (int k0 = 0; k0 < 512; k0 += 64) {
#pragma unroll
    for (int i = 0; i < 4; ++i) {
      const int r = brow + i * 32;
      *(uint4*)&As[r][bcg * 8] = *(const uint4*)&mqb[(size_t)(m0 + r) * 512 + k0 + bcg * 8];
      *(uint4*)&Bs[r][bcg * 8] = *(const uint4*)&kbb[(size_t)(n0 + r) * 512 + k0 + bcg * 8];
    }
    __syncthreads();
#pragma unroll
    for (int kk = 0; kk < 64; kk += 32) {
      bf16x8 af[4], bfv[4];
#pragma unroll
      for (int i = 0; i < 4; ++i) af[i] = *(const bf16x8*)&As[mqw + i * 16 + ml][kk + kl * 8];
#pragma unroll
      for (int j = 0; j < 4; ++j) bfv[j] = *(const bf16x8*)&Bs[nq + j * 16 + ml][kk + kl * 8];
#pragma unroll
      for (int i = 0; i < 4; ++i)
#pragma unroll
        for (int j = 0; j < 4; ++j)
          acc[i][j] = __builtin_amdgcn_mfma_f32_16x16x32_bf16(af[i], bfv[j], acc[i][j], 0, 0, 0);
    }
    __syncthreads();
  }
  float* outp = sc + ((size_t)bh * L_ + m0) * S_ + n0;
#pragma unroll
  for (int j = 0; j < 4; ++j) {
    const int gcl = nq + j * 16 + ml;
    const float cbv = cbuf[(size_t)bh * S_ + n0 + gcl];
#pragma unroll
    for (int i = 0; i < 4; ++i)
#pragma unroll
      for (int r = 0; r < 4; ++r) {
        const int grl = mqw + i * 16 + kl * 4 + r;
        outp[(size_t)grl * S_ + gcl] = (acc[i][j][r] + cbv) * 0.125f;
      }
  }
}

// ---------------------------------------------------------------------------
// Softmax + probs + ctx. 16 rows/block. Row slice cached in 64 packed-bf16
// VGPRs. Shuffle-only reductions. ctx GEMM: A from LDS (whole P half staged
// once), B loaded straight from global vT in B-fragment layout -> the 64-step
// MFMA loop has NO barriers (4 barriers per block total).
// ---------------------------------------------------------------------------
__global__ __launch_bounds__(256) void softmax_ctx(
    float* __restrict__ sc, const u16* __restrict__ vT, float* __restrict__ ctx)
{
  __shared__ u16 Ps[16][1032];   // row stride 2064B = 516 dw; 516%32=4 -> only free 2-way
  const int tid = threadIdx.x;
  const int bh = blockIdx.y, b = bh >> 3, h = bh & 7;
  const int l0 = blockIdx.x * 16;
  float* Sg = sc + ((size_t)bh * L_ + l0) * S_;
  const int row = tid >> 4, jg = tid & 15;   // 16 lanes per row, within one wave

  unsigned pr[64];
  float mx = -3.0e38f;
#pragma unroll
  for (int i = 0; i < 32; ++i) {
    const int c = jg * 4 + i * 64;
    float4 v = *(const float4*)&Sg[(size_t)row * S_ + c];
    pr[2 * i]     = (unsigned)f2bf(v.x) | ((unsigned)f2bf(v.y) << 16);
    pr[2 * i + 1] = (unsigned)f2bf(v.z) | ((unsigned)f2bf(v.w) << 16);
    mx = fmaxf(mx, fmaxf(fmaxf(v.x, v.y), fmaxf(v.z, v.w)));
  }
#pragma unroll
  for (int off = 8; off > 0; off >>= 1) mx = fmaxf(mx, __shfl_xor(mx, off, 64));
  float ls = 0.f;
#pragma unroll
  for (int i = 0; i < 64; ++i) {
    const unsigned u = pr[i];
    ls += __expf(bf2f((u16)(u & 0xFFFFu)) - mx) + __expf(bf2f((u16)(u >> 16)) - mx);
  }
#pragma unroll
  for (int off = 8; off > 0; off >>= 1) ls += __shfl_xor(ls, off, 64);
  const float rl = 1.0f / ls;

  const int lane = tid & 63, wv = tid >> 6;
  const int ml = lane & 15, kl = lane >> 4;
  const u16* vrow = vT + ((size_t)b * 512 + h * 64 + wv * 16 + ml) * S_ + kl * 8;
  floatx4 acc = {};

#pragma unroll
  for (int half = 0; half < 2; ++half) {
    __syncthreads();   // prior GEMM reads of Ps complete before overwrite
#pragma unroll
    for (int i = 0; i < 16; ++i) {
      const int ig = i + half * 16;
      const unsigned u0 = pr[2 * ig], u1 = pr[2 * ig + 1];
      float4 p;
      p.x = __expf(bf2f((u16)(u0 & 0xFFFFu)) - mx) * rl;
      p.y = __expf(bf2f((u16)(u0 >> 16)) - mx) * rl;
      p.z = __expf(bf2f((u16)(u1 & 0xFFFFu)) - mx) * rl;
      p.w = __expf(bf2f((u16)(u1 >> 16)) - mx) * rl;
      const int lc = jg * 4 + i * 64;
      *(float4*)&Sg[(size_t)row * S_ + half * 1024 + lc] = p;   // probs out
      uint2 t;
      t.x = (unsigned)f2bf(p.x) | ((unsigned)f2bf(p.y) << 16);
      t.y = (unsigned)f2bf(p.z) | ((unsigned)f2bf(p.w) << 16);
      *(uint2*)&Ps[row][lc] = t;
    }
    __syncthreads();
    const u16* vk = vrow + half * 1024;
#pragma unroll
    for (int k0 = 0; k0 < 1024; k0 += 32) {
      bf16x8 a  = *(const bf16x8*)&Ps[ml][k0 + kl * 8];
      bf16x8 bb = *(const bf16x8*)&vk[k0];
      acc = __builtin_amdgcn_mfma_f32_16x16x32_bf16(a, bb, acc, 0, 0, 0);
    }
  }
#pragma unroll
  for (int r = 0; r < 4; ++r)
    ctx[((size_t)b * L_ + l0 + kl * 4 + r) * 512 + h * 64 + wv * 16 + ml] = acc[r];
}

// ---------------------------------------------------------------------------
extern "C" void kernel_launch(void* const* d_in, const int* in_sizes, int n_in,
                              void* d_out, int out_size, void* d_ws, size_t ws_size,
                              hipStream_t stream) {
  const float* queries = (const float*)d_in[0];
  const float* keys    = (const float*)d_in[1];
  const float* values  = (const float*)d_in[2];
  const float* Wq  = (const float*)d_in[4];
  const float* Wk  = (const float*)d_in[5];
  const float* Wv  = (const float*)d_in[6];
  const float* bv  = (const float*)d_in[7];
  const float* Wcb = (const float*)d_in[8];
  const float* mixing = (const float*)d_in[9];
  const float* Wd  = (const float*)d_in[10];
  const float* bd  = (const float*)d_in[11];

  float* out   = (float*)d_out;                         // [B,L,512] fp32
  float* probs = out + (size_t)B_ * L_ * 512;           // [B,H,L,S] fp32

  char* ws = (char*)d_ws;
  u16*   qb  = (u16*)(ws);                              //  4 MB  bf16 [B*L,512]
  u16*   kb  = (u16*)(ws + (size_t)4  * 1024 * 1024);   //  4 MB  bf16 [B*S,512]
  u16*   vb  = (u16*)(ws + (size_t)8  * 1024 * 1024);   //  4 MB  bf16 [B*S,512]
  u16*   vT  = (u16*)(ws + (size_t)12 * 1024 * 1024);   //  4 MB  bf16 [B,512,S]
  float* cbuf= (float*)(ws + (size_t)16 * 1024 * 1024); // 128 KB fp32 [B,H,S]
  float* ctx = (float*)(ws + (size_t)17 * 1024 * 1024); //  8 MB  fp32 [B*L,512]
  u16*   mq  = (u16*)(ws + (size_t)25 * 1024 * 1024);   // 32 MB  bf16 [B,H,L,512]

  hipLaunchKernelGGL(qkv_gemm, dim3(4, 32, 3), dim3(256), 0, stream,
                     queries, keys, values, Wq, Wk, Wv, bv, qb, kb, vb);
  hipLaunchKernelGGL(mixq_kernel, dim3(1024), dim3(256), 0, stream, qb, mixing, mq);
  hipLaunchKernelGGL(cb_kernel, dim3(1024), dim3(256), 0, stream, keys, Wcb, cbuf);
  hipLaunchKernelGGL(transpose_v, dim3(8, 32, 2), dim3(256), 0, stream, vb, vT);
  hipLaunchKernelGGL(scores_gemm, dim3(16, 16, 16), dim3(256), 0, stream,
                     mq, kb, cbuf, probs);
  hipLaunchKernelGGL(softmax_ctx, dim3(128, 16), dim3(256), 0, stream,
                     probs, vT, ctx);
  hipLaunchKernelGGL(out_gemm, dim3(4, 32, 1), dim3(256), 0, stream,
                     ctx, Wd, bd, out);
}